// Round 9
// baseline (129.062 us; speedup 1.0000x reference)
//
#include <hip/hip_runtime.h>

#define B_TOTAL 16384
#define F_DIM 512
#define H_DIM 256
#define E_NUM 8
#define OUT_COLS 32
#define DA 8
#define TM 64                 // samples per mlp tile
#define HSTRIDE (H_DIM + 8)   // 264 halves: rows 16B-aligned
#define NBKT 32               // bucket blocks (segmented, no atomics)
#define SAMP_PER_BKT 512
#define SETUP_BLOCKS 424      // 256 W1-transpose + 128 W2-transpose + 8 W3 + 32 bucket
#define MLP_BLOCKS 264        // >= max total tiles (263)

typedef __attribute__((ext_vector_type(8))) _Float16 half8;
typedef __attribute__((ext_vector_type(4))) _Float16 half4;
typedef __attribute__((ext_vector_type(4))) float float4v;

// ---------------- merged setup: weight prep + segmented bucket (no atomics) ----------
// blocks 0..255: W1 64x64-tile transpose; 256..383: W2; 384..391: W3 pack;
// 392..423: bucket — each block counts+ranks its 512 samples via ballot and writes
// gcnt[bkt][e] and idxbuf[e][bkt*512+rank]. Every gcnt entry written unconditionally,
// so no memset dispatch and no global atomics are needed.
__global__ __launch_bounds__(512) void k_setup(
    const float* __restrict__ W1, const float* __restrict__ W2,
    const float* __restrict__ W3,
    _Float16* __restrict__ W1t, _Float16* __restrict__ W2t,
    _Float16* __restrict__ W3t,
    const int* __restrict__ act, int* __restrict__ gcnt,
    int* __restrict__ idxbuf) {
  int bid = blockIdx.x;
  int t = threadIdx.x;

  if (bid >= 392) {
    // ---- segmented bucket: per-wave ballot -> per-block counts + ranks ----
    __shared__ int wcnt[8][E_NUM];
    __shared__ int wbase[8][E_NUM];
    int lane = t & 63, wave = t >> 6;
    int bkt = bid - 392;
    int b = bkt * SAMP_PER_BKT + t;
    int e = act[b] & 7;

    unsigned long long mymask = 0;
#pragma unroll
    for (int v = 0; v < E_NUM; ++v) {
      unsigned long long m = __ballot(e == v);
      if (lane == 0) wcnt[wave][v] = (int)__popcll(m);
      if (e == v) mymask = m;
    }
    int rank = (int)__popcll(mymask & ((1ull << lane) - 1ull));
    __syncthreads();
    if (t < 64) {              // wave-base prefix within block: w=t>>3, e2=t&7
      int w = t >> 3, e2 = t & 7, sacc = 0;
      for (int w2 = 0; w2 < w; ++w2) sacc += wcnt[w2][e2];
      wbase[w][e2] = sacc;
    }
    if (t < E_NUM) {
      int sacc = 0;
#pragma unroll
      for (int w2 = 0; w2 < 8; ++w2) sacc += wcnt[w2][t];
      gcnt[bkt * E_NUM + t] = sacc;
    }
    __syncthreads();
    idxbuf[e * B_TOTAL + bkt * SAMP_PER_BKT + wbase[wave][e] + rank] = b;
    return;
  }

  if (bid >= 384) {            // W3: (256,32) -> (16,256) with rows 8..15 = 0
    int e = bid - 384;
    int k = t & 255, o0 = (t >> 8) * 8;
#pragma unroll
    for (int i = 0; i < 8; ++i) {
      int o = o0 + i;
      float v = (o < DA) ? W3[((size_t)e * H_DIM + k) * OUT_COLS + o] : 0.f;
      W3t[((size_t)e * 16 + o) * H_DIM + k] = (_Float16)v;
    }
    return;
  }

  // ---- 64x64 weight transpose tile (fp32 -> fp16), one barrier, 512 threads ----
  __shared__ _Float16 hs[64][80];
  int e, tt, K;
  const float* S; _Float16* D;
  if (bid < 256) { e = bid >> 5; tt = bid & 31; K = F_DIM;     // 8 k-tiles x 4 h-tiles
    S = W1 + (size_t)e * F_DIM * H_DIM; D = W1t + (size_t)e * H_DIM * F_DIM; }
  else { int r_ = bid - 256; e = r_ >> 4; tt = r_ & 15; K = H_DIM;  // 4 x 4
    S = W2 + (size_t)e * H_DIM * H_DIM; D = W2t + (size_t)e * H_DIM * H_DIM; }
  int k0 = (tt >> 2) * 64, h0 = (tt & 3) * 64;
  int r = t >> 3, j = t & 7;               // 8 threads per source row
  const float* srow = S + (size_t)(k0 + r) * H_DIM + h0 + j * 8;
  float4v v0 = __builtin_nontemporal_load((const float4v*)srow);
  float4v v1 = __builtin_nontemporal_load((const float4v*)(srow + 4));
  int c = j * 8;
  hs[c + 0][r] = (_Float16)v0.x; hs[c + 1][r] = (_Float16)v0.y;
  hs[c + 2][r] = (_Float16)v0.z; hs[c + 3][r] = (_Float16)v0.w;
  hs[c + 4][r] = (_Float16)v1.x; hs[c + 5][r] = (_Float16)v1.y;
  hs[c + 6][r] = (_Float16)v1.z; hs[c + 7][r] = (_Float16)v1.w;
  __syncthreads();
  _Float16* drow = D + (size_t)(h0 + r) * K + k0 + j * 8;
  *(half8*)drow = *(const half8*)&hs[r][j * 8];
}

// ---------------- fused gather + 3-layer expert MLP (TM=64, segmented idxbuf) -------
// 264 blocks x 16 waves (1024 thr). Weight-stall elimination: L1 A-operands via a
// DEPTH-8 modulo register pipeline (issue distance ~8 iters >= L3 latency); L2
// A-operands fully register-resident (one 8-load burst after the L1 loop, consumed
// with static indexing — zero memory dependencies inside the L2 loop).
__global__ __launch_bounds__(1024, 4) void k_mlp(
    const float* __restrict__ X,
    const _Float16* __restrict__ W1t,
    const _Float16* __restrict__ W2t,
    const _Float16* __restrict__ W3t,
    const float* __restrict__ b1,
    const float* __restrict__ b2,
    const float* __restrict__ b3,
    const int* __restrict__ gcnt,
    const int* __restrict__ idxbuf,
    float* __restrict__ out)
{
  __shared__ _Float16 bufA[TM][HSTRIDE];  // X cols 0..255 -> later H2 (33792 B)
  __shared__ _Float16 bufB[TM][HSTRIDE];  // X cols 256..511 -> later H1
  __shared__ int gl[NBKT * E_NUM];
  __shared__ int Pl[E_NUM][NBKT + 1];     // exclusive per-bucket prefix per expert

  int t = threadIdx.x;
  int lane = t & 63;
  int wave = t >> 6;          // 0..15
  int quad = lane >> 4;
  int l16 = lane & 15;
  int hbase = wave * 16;      // 16 hidden rows per wave
  int kq = quad * 8;
  int s = t >> 4, sub = t & 15;   // staging: 16 threads per sample row

  // --- root of the chain: load gcnt, build prefix table (unrolled: loads batch) ---
  if (t < NBKT * E_NUM) gl[t] = gcnt[t];
  __syncthreads();
  if (t < E_NUM) {
    int v[NBKT];
#pragma unroll
    for (int b2 = 0; b2 < NBKT; ++b2) v[b2] = gl[b2 * E_NUM + t];
    int acc0 = 0;
#pragma unroll
    for (int b2 = 0; b2 < NBKT; ++b2) { Pl[t][b2] = acc0; acc0 += v[b2]; }
    Pl[t][NBKT] = acc0;
  }
  __syncthreads();

  int counts_r[E_NUM];
#pragma unroll
  for (int j = 0; j < E_NUM; ++j) counts_r[j] = Pl[j][NBKT];

  // --- compact map: tile = blockIdx.x over 64-rounded per-expert regions ---
  int slot0 = blockIdx.x * TM;
  int base = 0, e = 0, tile0 = -1, cnt = 0;
#pragma unroll
  for (int j = 0; j < E_NUM; ++j) {
    int rc = (counts_r[j] + TM - 1) & ~(TM - 1);
    if (tile0 < 0) {
      if (slot0 < base + rc) { e = j; tile0 = slot0 - base; cnt = counts_r[j]; }
      else base += rc;
    }
  }
  if (tile0 < 0) return;

  const float4v vzero = {0.f, 0.f, 0.f, 0.f};
  int si = tile0 + s;
  bool valid = si < cnt;
  // branchless segment search: bkt = #{b2 in [1,NBKT) : Pl[e][b2] <= si}
  int bkt = 0;
#pragma unroll
  for (int b2 = 1; b2 < NBKT; ++b2) bkt += (Pl[e][b2] <= si) ? 1 : 0;
  int xrow = valid ? idxbuf[e * B_TOTAL + bkt * SAMP_PER_BKT + (si - Pl[e][bkt])] : 0;
  const float* src = X + (size_t)xrow * F_DIM + sub * 4;

  // --- X gather: all 8 float4 issued together, non-temporal ---
  float4v xr[8];
#pragma unroll
  for (int i = 0; i < 8; ++i)
    xr[i] = __builtin_nontemporal_load((const float4v*)(src + i * 64));

  // --- layer-1 weight prefetch: DEPTH-8 modulo pipeline, issued while X in flight ---
  const _Float16* wb = W1t + ((size_t)e * H_DIM + hbase + l16) * F_DIM + kq;
  half8 a_p[8];
#pragma unroll
  for (int p = 0; p < 8; ++p)
    a_p[p] = *(const half8*)(wb + p * 32);

  // --- land X: chunk0 -> bufA, chunk1 -> bufB ---
#pragma unroll
  for (int i = 0; i < 8; ++i) {
    int c = sub * 4 + i * 64;
    float4v v = valid ? xr[i] : vzero;
    half4 h;
    h[0] = (_Float16)v.x; h[1] = (_Float16)v.y;
    h[2] = (_Float16)v.z; h[3] = (_Float16)v.w;
    if (i < 4) *(half4*)&bufA[s][c] = h;
    else       *(half4*)&bufB[s][c - 256] = h;
  }
  __syncthreads();

  float4v acc[4];
#pragma unroll
  for (int st = 0; st < 4; ++st) acc[st] = vzero;

  // ======== Layer 1: 16 K-iterations over bufA then bufB (depth-8 refills) ========
#pragma unroll
  for (int kb = 0; kb < F_DIM; kb += 32) {
    int p = (kb >> 5) & 7;
    half8 a_cur = a_p[p];
    if (kb + 256 < F_DIM)
      a_p[p] = *(const half8*)(wb + kb + 256);
    half8 b_cur[4];
    if (kb < 256) {
#pragma unroll
      for (int st = 0; st < 4; ++st)
        b_cur[st] = *(const half8*)&bufA[st * 16 + l16][kb + kq];
    } else {
#pragma unroll
      for (int st = 0; st < 4; ++st)
        b_cur[st] = *(const half8*)&bufB[st * 16 + l16][kb - 256 + kq];
    }
#pragma unroll
    for (int st = 0; st < 4; ++st)
      acc[st] = __builtin_amdgcn_mfma_f32_16x16x32_f16(a_cur, b_cur[st], acc[st], 0, 0, 0);
  }

  // --- layer-2 weights: FULL register burst (8 x half8); lands during epilogue ---
  const _Float16* wb2 = W2t + ((size_t)e * H_DIM + hbase + l16) * H_DIM + kq;
  half8 w2[8];
#pragma unroll
  for (int p = 0; p < 8; ++p)
    w2[p] = *(const half8*)(wb2 + p * 32);

  __syncthreads();  // all waves done reading bufB as X before H1 lands there

  // layer-1 epilogue: bias + relu -> bufB (= H1[sample][hidden])
  {
    int h0 = hbase + quad * 4;
    float4v bb = *(const float4v*)&b1[e * H_DIM + h0];
#pragma unroll
    for (int st = 0; st < 4; ++st) {
      half4 hv;
#pragma unroll
      for (int r = 0; r < 4; ++r) {
        float v = acc[st][r] + bb[r];
        hv[r] = (_Float16)(v > 0.f ? v : 0.f);
      }
      *(half4*)&bufB[st * 16 + l16][h0] = hv;
    }
  }
  __syncthreads();

  // ======== Layer 2: zero memory deps — weights in registers, static index ========
#pragma unroll
  for (int st = 0; st < 4; ++st) acc[st] = vzero;

#pragma unroll
  for (int kb = 0; kb < H_DIM; kb += 32) {
    half8 a_cur = w2[kb >> 5];        // compile-time index after unroll
    half8 b_cur[4];
#pragma unroll
    for (int st = 0; st < 4; ++st)
      b_cur[st] = *(const half8*)&bufB[st * 16 + l16][kb + kq];
#pragma unroll
    for (int st = 0; st < 4; ++st)
      acc[st] = __builtin_amdgcn_mfma_f32_16x16x32_f16(a_cur, b_cur[st], acc[st], 0, 0, 0);
  }

  // layer-2 epilogue -> bufA (= H2; X chunk0 dead — all waves past barrier 2)
  {
    int h0 = hbase + quad * 4;
    float4v bb = *(const float4v*)&b2[e * H_DIM + h0];
#pragma unroll
    for (int st = 0; st < 4; ++st) {
      half4 hv;
#pragma unroll
      for (int r = 0; r < 4; ++r) {
        float v = acc[st][r] + bb[r];
        hv[r] = (_Float16)(v > 0.f ? v : 0.f);
      }
      *(half4*)&bufA[st * 16 + l16][h0] = hv;
    }
  }

  // --- waves 0..3: prefetch W3 before the barrier (reuses dead a_p/w2 regs) ---
  half8 af[8];
  const _Float16* wb3 = W3t + ((size_t)e * 16 + l16) * H_DIM + kq;
  if (wave < 4) {
#pragma unroll
    for (int i = 0; i < 8; ++i) af[i] = *(const half8*)(wb3 + i * 32);
  }
  __syncthreads();

  // ======== Layer 3: waves 0..3 each compute one 16-sample out tile ========
  if (wave < 4) {
    float4v acc3 = vzero;
#pragma unroll
    for (int i = 0; i < 8; ++i) {
      half8 bfrag = *(const half8*)&bufA[wave * 16 + l16][i * 32 + kq];
      acc3 = __builtin_amdgcn_mfma_f32_16x16x32_f16(af[i], bfrag, acc3, 0, 0, 0);
    }
    int si3 = tile0 + wave * 16 + l16;
    if (quad < 2 && si3 < cnt) {
      int bkt3 = 0;
#pragma unroll
      for (int b2 = 1; b2 < NBKT; ++b2) bkt3 += (Pl[e][b2] <= si3) ? 1 : 0;
      int row = idxbuf[e * B_TOTAL + bkt3 * SAMP_PER_BKT + (si3 - Pl[e][bkt3])];
      float4v bb = *(const float4v*)&b3[e * OUT_COLS + quad * 4];
      float4v y;
#pragma unroll
      for (int r = 0; r < 4; ++r) y[r] = acc3[r] + bb[r];
      __builtin_nontemporal_store(y, (float4v*)&out[(size_t)row * DA + quad * 4]);
    }
  }
}

extern "C" void kernel_launch(void* const* d_in, const int* in_sizes, int n_in,
                              void* d_out, int out_size, void* d_ws, size_t ws_size,
                              hipStream_t stream) {
  const float* features = (const float*)d_in[0];
  const float* W1 = (const float*)d_in[1];
  const float* b1 = (const float*)d_in[2];
  const float* W2 = (const float*)d_in[3];
  const float* b2 = (const float*)d_in[4];
  const float* W3 = (const float*)d_in[5];
  const float* b3 = (const float*)d_in[6];
  const int* act = (const int*)d_in[7];
  float* out = (float*)d_out;

  char* ws = (char*)d_ws;
  int* idxbuf = (int*)ws;                                      // 512 KiB
  _Float16* W1t = (_Float16*)(ws + 524288);                    // 2 MiB
  _Float16* W2t = (_Float16*)(ws + 524288 + 2097152);          // 1 MiB
  _Float16* W3t = (_Float16*)(ws + 524288 + 2097152 + 1048576);        // 64 KiB
  int* gcnt = (int*)(ws + 524288 + 2097152 + 1048576 + 65536);         // 1 KiB

  // two dispatches total: no memset (segmented bucket writes all state unconditionally)
  k_setup<<<SETUP_BLOCKS, 512, 0, stream>>>(W1, W2, W3, W1t, W2t, W3t,
                                            act, gcnt, idxbuf);
  k_mlp<<<MLP_BLOCKS, 1024, 0, stream>>>(features, W1t, W2t, W3t,
                                         b1, b2, b3, gcnt, idxbuf, out);
}

// Round 10
// 125.461 us; speedup vs baseline: 1.0287x; 1.0287x over previous
//
#include <hip/hip_runtime.h>

#define B_TOTAL 16384
#define F_DIM 512
#define H_DIM 256
#define E_NUM 8
#define OUT_COLS 32
#define DA 8
#define TM 64                 // samples per block
#define HSTRIDE (H_DIM + 8)   // 264 halves: rows 16B-aligned
#define C_CAP 36              // per-expert tile capacity; 8*36=288 >= max total tiles (263)
#define MLP_BLOCKS (E_NUM * C_CAP)  // 288
#define SETUP_BLOCKS 456      // 256 W1-transpose + 128 W2-transpose + 8 W3 + 64 bucket

typedef __attribute__((ext_vector_type(8))) _Float16 half8;
typedef __attribute__((ext_vector_type(4))) _Float16 half4;
typedef __attribute__((ext_vector_type(4))) float float4v;

// ---------------- merged setup: weight prep + bucket in one dispatch ----------------
// XCD-aligned: transpose/pack blocks for expert e have (bid&7)==e, so expert e's fp16
// weights are written through XCD e's L2 and stay resident for k_mlp (whose blocks for
// expert e also land on XCD e).
// blocks 0..255: W1 64x64-tile transpose (32 tiles/e); 256..383: W2 (16 tiles/e);
// 384..391: W3 pack; 392..455: bucket.
__global__ void k_setup(const float* __restrict__ W1, const float* __restrict__ W2,
                        const float* __restrict__ W3,
                        _Float16* __restrict__ W1t, _Float16* __restrict__ W2t,
                        _Float16* __restrict__ W3t,
                        const int* __restrict__ act, int* __restrict__ counts,
                        int* __restrict__ idxbuf) {
  int bid = blockIdx.x;
  if (bid >= 392) {
    // ---- bucket samples by expert (block-aggregated atomics) ----
    __shared__ int wcnt[4][E_NUM];
    __shared__ int wbase[4][E_NUM];
    int t = threadIdx.x;
    int lane = t & 63, wave = t >> 6;
    int b = (bid - 392) * 256 + t;
    int e = act[b] & 7;

    unsigned long long mymask = 0;
#pragma unroll
    for (int v = 0; v < E_NUM; ++v) {
      unsigned long long m = __ballot(e == v);
      if (lane == 0) wcnt[wave][v] = (int)__popcll(m);
      if (e == v) mymask = m;
    }
    int rank = (int)__popcll(mymask & ((1ull << lane) - 1ull));
    __syncthreads();
    if (t < E_NUM) {
      int c0 = wcnt[0][t], c1 = wcnt[1][t], c2 = wcnt[2][t], c3 = wcnt[3][t];
      int base = atomicAdd(&counts[t], c0 + c1 + c2 + c3);
      wbase[0][t] = base;
      wbase[1][t] = base + c0;
      wbase[2][t] = base + c0 + c1;
      wbase[3][t] = base + c0 + c1 + c2;
    }
    __syncthreads();
    idxbuf[e * B_TOTAL + wbase[wave][e] + rank] = b;
    return;
  }

  if (bid >= 384) {            // W3: (256,32) -> (16,256) with rows 8..15 = 0
    int e = bid - 384;         // == bid&7: XCD-aligned
    int k = threadIdx.x;
#pragma unroll
    for (int o = 0; o < 16; ++o) {
      float v = (o < DA) ? W3[((size_t)e * H_DIM + k) * OUT_COLS + o] : 0.f;
      W3t[((size_t)e * 16 + o) * H_DIM + k] = (_Float16)v;
    }
    return;
  }

  // ---- weight transpose: one 64x64 tile per block, expert = bid&7 ----
  __shared__ _Float16 hs[64][72];   // hs[h][k], +8 pad
  int t = threadIdx.x;
  int r = t >> 2, j = t & 3;        // r: source row (k), 4 threads per row
  int e = bid & 7;
  const float* S; _Float16* D; int K, tile;
  if (bid < 256) {                  // W1: (512,256) -> (256,512); 8 k-tiles x 4 h-tiles
    tile = bid >> 3; K = F_DIM;
    S = W1 + (size_t)e * F_DIM * H_DIM;
    D = W1t + (size_t)e * H_DIM * F_DIM;
  } else {                          // W2: (256,256) -> (256,256); 4 k-tiles x 4 h-tiles
    tile = (bid - 256) >> 3; K = H_DIM;
    S = W2 + (size_t)e * H_DIM * H_DIM;
    D = W2t + (size_t)e * H_DIM * H_DIM;
  }
  int k0 = (tile >> 2) * 64, h0 = (tile & 3) * 64;

  const float* srow = S + (size_t)(k0 + r) * H_DIM + h0;
  float4v v[4];
#pragma unroll
  for (int i = 0; i < 4; ++i)       // all 4 reads issued together: one latency event
    v[i] = *(const float4v*)(srow + (j + 4 * i) * 4);
#pragma unroll
  for (int i = 0; i < 4; ++i) {
    int c = (j + 4 * i) * 4;        // source col = h index
    hs[c + 0][r] = (_Float16)v[i].x;
    hs[c + 1][r] = (_Float16)v[i].y;
    hs[c + 2][r] = (_Float16)v[i].z;
    hs[c + 3][r] = (_Float16)v[i].w;
  }
  __syncthreads();
  _Float16* drow = D + (size_t)(h0 + r) * K + k0;   // r now: dest row (h)
#pragma unroll
  for (int i = 0; i < 2; ++i)
    *(half8*)(drow + (j + 4 * i) * 8) = *(const half8*)&hs[r][(j + 4 * i) * 8];
}

// ---------------- fused gather + 3-layer expert MLP (XCD-pinned, TM=64) -------------
// 288 blocks x 16 waves (1024 thr). Block bid -> expert (bid&7), tile (bid>>3):
// round-robin dispatch lands expert e's blocks on XCD e, whose L2 holds e's weights
// (written there by k_setup). Wave owns 16 hidden rows x 64 samples (4 s-tiles).
// X loads / out stores are non-temporal so streaming X doesn't evict pinned weights.
// Orphan remap covers expert skew (provably: 8*C_CAP=288 >= total tiles <= 263).
__global__ __launch_bounds__(1024, 4) void k_mlp(
    const float* __restrict__ X,
    const _Float16* __restrict__ W1t,
    const _Float16* __restrict__ W2t,
    const _Float16* __restrict__ W3t,
    const float* __restrict__ b1,
    const float* __restrict__ b2,
    const float* __restrict__ b3,
    const int* __restrict__ counts,
    const int* __restrict__ idxbuf,
    float* __restrict__ out)
{
  __shared__ _Float16 bufA[TM][HSTRIDE];  // X cols 0..255 -> later H2 (33792 B)
  __shared__ _Float16 bufB[TM][HSTRIDE];  // X cols 256..511 -> later H1

  int t = threadIdx.x;
  int lane = t & 63;
  int wave = t >> 6;          // 0..15
  int quad = lane >> 4;
  int l16 = lane & 15;
  int hbase = wave * 16;      // 16 hidden rows per wave
  int kq = quad * 8;
  int s = t >> 4, sub = t & 15;   // staging: 16 threads per sample row

  int x = blockIdx.x & 7;
  int li = blockIdx.x >> 3;   // 0..35

  // --- speculative idxbuf load (primary mapping), issued at cycle 0 ---
  int raw = idxbuf[x * B_TOTAL + li * TM + s];

  // --- counts (uniform) + primary/orphan mapping ---
  int cnt_x = counts[x];
  int tt_x = (cnt_x + TM - 1) >> 6;
  int e = x, tile = li, cnt = cnt_x;
  if (li >= tt_x) {
    // orphan remap (handles skewed expert distributions; uniform per block)
    int ttj[E_NUM];
#pragma unroll
    for (int j = 0; j < E_NUM; ++j) ttj[j] = (counts[j] + TM - 1) >> 6;
    int rank = 0;
#pragma unroll
    for (int j = 0; j < E_NUM; ++j) { int d = li - ttj[j]; rank += d > 0 ? d : 0; }
#pragma unroll
    for (int j = 0; j < E_NUM; ++j) if (j < x && li >= ttj[j]) ++rank;
    int fe = -1, ft = 0, accum = 0;
#pragma unroll
    for (int j = 0; j < E_NUM; ++j) {
      int lo = ttj[j] - C_CAP; lo = lo > 0 ? lo : 0;
      if (fe < 0 && rank < accum + lo) { fe = j; ft = C_CAP + (rank - accum); }
      accum += lo;
    }
    if (fe < 0) return;
    e = fe; tile = ft; cnt = counts[e];
    raw = idxbuf[e * B_TOTAL + tile * TM + s];
  }
  int tile0 = tile * TM;

  const float4v vzero = {0.f, 0.f, 0.f, 0.f};
  bool valid = (tile0 + s) < cnt;
  int xrow = raw & (B_TOTAL - 1);   // clamp: speculative entries may be garbage
  const float* src = X + (size_t)xrow * F_DIM + sub * 4;

  // --- X gather: all 8 float4 issued together, non-temporal (no L2 pollution) ---
  float4v xr[8];
#pragma unroll
  for (int i = 0; i < 8; ++i)
    xr[i] = __builtin_nontemporal_load((const float4v*)(src + i * 64));

  // --- layer-1 weight prefetch (depth-5 modulo pipeline), issued while X in flight ---
  const _Float16* wb = W1t + ((size_t)e * H_DIM + hbase + l16) * F_DIM + kq;
  half8 a_p[5];
#pragma unroll
  for (int p = 0; p < 5; ++p)
    a_p[p] = *(const half8*)(wb + p * 32);

  // --- land X: chunk0 -> bufA, chunk1 -> bufB ---
#pragma unroll
  for (int i = 0; i < 8; ++i) {
    int c = sub * 4 + i * 64;
    float4v v = valid ? xr[i] : vzero;
    half4 h;
    h[0] = (_Float16)v.x; h[1] = (_Float16)v.y;
    h[2] = (_Float16)v.z; h[3] = (_Float16)v.w;
    if (i < 4) *(half4*)&bufA[s][c] = h;
    else       *(half4*)&bufB[s][c - 256] = h;
  }
  __syncthreads();

  float4v acc[4];
#pragma unroll
  for (int st = 0; st < 4; ++st) acc[st] = vzero;

  // ======== Layer 1: 16 K-iterations over bufA then bufB ========
#pragma unroll
  for (int kb = 0; kb < F_DIM; kb += 32) {
    int p = (kb >> 5) % 5;
    half8 a_cur = a_p[p];
    if (kb + 160 < F_DIM)
      a_p[p] = *(const half8*)(wb + kb + 160);
    half8 b_cur[4];
    if (kb < 256) {
#pragma unroll
      for (int st = 0; st < 4; ++st)
        b_cur[st] = *(const half8*)&bufA[st * 16 + l16][kb + kq];
    } else {
#pragma unroll
      for (int st = 0; st < 4; ++st)
        b_cur[st] = *(const half8*)&bufB[st * 16 + l16][kb - 256 + kq];
    }
#pragma unroll
    for (int st = 0; st < 4; ++st)
      acc[st] = __builtin_amdgcn_mfma_f32_16x16x32_f16(a_cur, b_cur[st], acc[st], 0, 0, 0);
  }

  // --- issue layer-2 weight prefetch (depth-5) before barrier ---
  const _Float16* wb2 = W2t + ((size_t)e * H_DIM + hbase + l16) * H_DIM + kq;
#pragma unroll
  for (int p = 0; p < 5; ++p)
    a_p[p] = *(const half8*)(wb2 + p * 32);

  __syncthreads();  // all waves done reading bufB as X before H1 lands there

  // layer-1 epilogue: bias + relu -> bufB (= H1[sample][hidden])
  {
    int h0 = hbase + quad * 4;
    float4v bb = *(const float4v*)&b1[e * H_DIM + h0];
#pragma unroll
    for (int st = 0; st < 4; ++st) {
      half4 hv;
#pragma unroll
      for (int r = 0; r < 4; ++r) {
        float v = acc[st][r] + bb[r];
        hv[r] = (_Float16)(v > 0.f ? v : 0.f);
      }
      *(half4*)&bufB[st * 16 + l16][h0] = hv;
    }
  }
  __syncthreads();

  // ======== Layer 2: H2^T[h][s] = sum_k W2t[h][k] * H1[s][k] ========
#pragma unroll
  for (int st = 0; st < 4; ++st) acc[st] = vzero;

#pragma unroll
  for (int kb = 0; kb < H_DIM; kb += 32) {
    int p = (kb >> 5) % 5;
    half8 a_cur = a_p[p];
    if (kb + 160 < H_DIM)
      a_p[p] = *(const half8*)(wb2 + kb + 160);
    half8 b_cur[4];
#pragma unroll
    for (int st = 0; st < 4; ++st)
      b_cur[st] = *(const half8*)&bufB[st * 16 + l16][kb + kq];
#pragma unroll
    for (int st = 0; st < 4; ++st)
      acc[st] = __builtin_amdgcn_mfma_f32_16x16x32_f16(a_cur, b_cur[st], acc[st], 0, 0, 0);
  }

  // layer-2 epilogue -> bufA (= H2; X chunk0 dead — all waves past barrier 2)
  {
    int h0 = hbase + quad * 4;
    float4v bb = *(const float4v*)&b2[e * H_DIM + h0];
#pragma unroll
    for (int st = 0; st < 4; ++st) {
      half4 hv;
#pragma unroll
      for (int r = 0; r < 4; ++r) {
        float v = acc[st][r] + bb[r];
        hv[r] = (_Float16)(v > 0.f ? v : 0.f);
      }
      *(half4*)&bufA[st * 16 + l16][h0] = hv;
    }
  }

  // --- waves 0..3: prefetch W3 before the barrier ---
  half8 af[8];
  const _Float16* wb3 = W3t + ((size_t)e * 16 + l16) * H_DIM + kq;
  if (wave < 4) {
#pragma unroll
    for (int i = 0; i < 8; ++i) af[i] = *(const half8*)(wb3 + i * 32);
  }
  __syncthreads();

  // ======== Layer 3: waves 0..3 each compute one 16-sample out tile ========
  if (wave < 4) {
    float4v acc3 = vzero;
#pragma unroll
    for (int i = 0; i < 8; ++i) {
      half8 bfrag = *(const half8*)&bufA[wave * 16 + l16][i * 32 + kq];
      acc3 = __builtin_amdgcn_mfma_f32_16x16x32_f16(af[i], bfrag, acc3, 0, 0, 0);
    }
    int si = tile0 + wave * 16 + l16;
    if (quad < 2 && si < cnt) {
      int row = idxbuf[e * B_TOTAL + si];
      float4v bb = *(const float4v*)&b3[e * OUT_COLS + quad * 4];
      float4v y;
#pragma unroll
      for (int r = 0; r < 4; ++r) y[r] = acc3[r] + bb[r];
      __builtin_nontemporal_store(y, (float4v*)&out[(size_t)row * DA + quad * 4]);
    }
  }
}

extern "C" void kernel_launch(void* const* d_in, const int* in_sizes, int n_in,
                              void* d_out, int out_size, void* d_ws, size_t ws_size,
                              hipStream_t stream) {
  const float* features = (const float*)d_in[0];
  const float* W1 = (const float*)d_in[1];
  const float* b1 = (const float*)d_in[2];
  const float* W2 = (const float*)d_in[3];
  const float* b2 = (const float*)d_in[4];
  const float* W3 = (const float*)d_in[5];
  const float* b3 = (const float*)d_in[6];
  const int* act = (const int*)d_in[7];
  float* out = (float*)d_out;

  char* ws = (char*)d_ws;
  int* counts = (int*)ws;                                      // 256 B
  int* idxbuf = (int*)(ws + 256);                              // 512 KiB
  _Float16* W1t = (_Float16*)(ws + 256 + 524288);              // 2 MiB
  _Float16* W2t = (_Float16*)(ws + 256 + 524288 + 2097152);    // 1 MiB
  _Float16* W3t = (_Float16*)(ws + 256 + 524288 + 2097152 + 1048576);  // 64 KiB

  hipMemsetAsync(counts, 0, 256, stream);
  k_setup<<<SETUP_BLOCKS, 256, 0, stream>>>(W1, W2, W3, W1t, W2t, W3t,
                                            act, counts, idxbuf);
  k_mlp<<<MLP_BLOCKS, 1024, 0, stream>>>(features, W1t, W2t, W3t,
                                         b1, b2, b3, counts, idxbuf, out);
}